// Round 6
// baseline (128.587 us; speedup 1.0000x reference)
//
#include <hip/hip_runtime.h>
#include <hip/hip_bf16.h>

// SpatialCrossBranchAttention — bf16 MFMA v6
// B=4, C=64, C8=8, N=4096.
// ws (ushort bf16): qg[B*N*8] | kg[B*N*8] | vtg[B*C*N]  = 2.5 MB
//
// attn: swapped QK^T (S^T = K*Q^T) via mfma_f32_32x32x16_bf16; K=16 padding
// carried entirely by the zeroed Q-half (K side needs no mask: 0*garbage=0).
// Q pre-scaled by log2(e) in proj so numerators are bare v_exp_f32 (exp2).
// PV as O^T = V^T * P^T; P^T D-layout -> B-frag via cvt_pk + shfl_xor(32).
// V/K read directly from global with one-chunk register prefetch; the two
// tile-waves of each key-quarter share their stream through L1, paced by a
// raw s_barrier per chunk. 8 waves/block = 2 waves/SIMD for TLP.

typedef __attribute__((ext_vector_type(8)))  short s16x8;
typedef __attribute__((ext_vector_type(16))) float f32x16;

constexpr int B  = 4;
constexpr int C  = 64;
constexpr int N  = 4096;
constexpr int CH = 32;   // keys per chunk
constexpr int NC = 32;   // chunks per key-quarter (1024/32)

__device__ __forceinline__ ushort f2bf(float x) {
    union { __hip_bfloat16 h; ushort u; } cv;
    cv.h = __float2bfloat16(x);
    return cv.u;
}
__device__ __forceinline__ uint pk2(float a, float b) {   // -> v_cvt_pk_bf16_f32
    union { __hip_bfloat162 h2; uint u; } cv;
    cv.h2.x = __float2bfloat16(a);
    cv.h2.y = __float2bfloat16(b);
    return cv.u;
}
__device__ __forceinline__ float exp2_fast(float x) {
#if __has_builtin(__builtin_amdgcn_exp2f)
    return __builtin_amdgcn_exp2f(x);
#else
    float e;
    asm("v_exp_f32 %0, %1" : "=v"(e) : "v"(x));
    return e;
#endif
}

// ---------------------------------------------------------------------------
// Projections. Block = 320 threads = 10 groups x 32 tokens.
// grp 0..7: v channels grp*8..+7 (from xs) -> vtg (B,C,N) bf16
// grp 8   : k (from xs)                    -> kg  (B,N,8) bf16
// grp 9   : q (from xt), PRE-SCALED log2e  -> qg  (B,N,8) bf16
// ---------------------------------------------------------------------------
__global__ __launch_bounds__(320) void proj_kernel(
    const float* __restrict__ xs, const float* __restrict__ xt,
    const float* __restrict__ Wq, const float* __restrict__ bq,
    const float* __restrict__ Wk, const float* __restrict__ bk,
    const float* __restrict__ Wv, const float* __restrict__ bv,
    ushort* __restrict__ qg, ushort* __restrict__ kg, ushort* __restrict__ vtg)
{
    const int tid = threadIdx.x;
    const int grp = tid >> 5;                 // 0..9
    const int tok = tid & 31;
    const int b   = blockIdx.x >> 7;          // 128 blocks per batch
    const int n   = ((blockIdx.x & 127) << 5) + tok;

    const float* Wsel; const float* bsel; const float* xsel;
    if (grp < 8)       { Wsel = Wv + grp * 8 * C; bsel = bv + grp * 8; xsel = xs; }
    else if (grp == 8) { Wsel = Wk;               bsel = bk;           xsel = xs; }
    else               { Wsel = Wq;               bsel = bq;           xsel = xt; }

    float acc[8];
#pragma unroll
    for (int j = 0; j < 8; j++) acc[j] = bsel[j];

    const float* xcol = xsel + (size_t)b * C * N + n;
#pragma unroll 2
    for (int ci = 0; ci < C; ci += 4) {
        float x0 = xcol[(size_t)(ci + 0) * N];
        float x1 = xcol[(size_t)(ci + 1) * N];
        float x2 = xcol[(size_t)(ci + 2) * N];
        float x3 = xcol[(size_t)(ci + 3) * N];
#pragma unroll
        for (int j = 0; j < 8; j++) {
            const float4 w4 = *(const float4*)&Wsel[j * C + ci];
            acc[j] += w4.x * x0 + w4.y * x1 + w4.z * x2 + w4.w * x3;
        }
    }

    if (grp < 8) {
#pragma unroll
        for (int j = 0; j < 8; j++)
            vtg[((size_t)b * C + grp * 8 + j) * N + n] = f2bf(acc[j]);
    } else {
        if (grp == 9) {   // fold log2(e) into Q so softmax uses raw exp2
#pragma unroll
            for (int j = 0; j < 8; j++) acc[j] *= 1.4426950408889634f;
        }
        uint4 wv;
        wv.x = pk2(acc[0], acc[1]); wv.y = pk2(acc[2], acc[3]);
        wv.z = pk2(acc[4], acc[5]); wv.w = pk2(acc[6], acc[7]);
        ushort* dst = (grp == 8 ? kg : qg) + ((size_t)b * N + n) * 8;
        *(uint4*)dst = wv;
    }
}

// ---------------------------------------------------------------------------
// Attention. Block = 512 threads = 8 waves: tile = w>>2 (2 query tiles of 32),
// quarter = w&3 (4 key quarters of 1024). Grid = B*64 = 256 blocks (1/CU),
// 2 waves/SIMD. The 2 tile-waves of a quarter share the K/V stream via L1.
// ---------------------------------------------------------------------------
__global__ __launch_bounds__(512, 2) void attn_kernel(
    const ushort* __restrict__ qg, const ushort* __restrict__ kg,
    const ushort* __restrict__ vtg, const float* __restrict__ xt,
    const float* __restrict__ gamma, float* __restrict__ out)
{
    __shared__ float comb[2][3][64][33];   // 4-way combine, 49.5 KB, 33-stride
    __shared__ float combd[2][3][32];      // partial denominators

    const int tid  = threadIdx.x;
    const int w    = tid >> 6;        // 0..7
    const int l    = tid & 63;
    const int q32  = l & 31;
    const int G    = l >> 5;          // lane half-group
    const bool g1  = (G != 0);

    // XCD-aware decode: xcd = bid & 7; 2 XCDs per batch; bijective (256=32x8).
    const int bid  = blockIdx.x;
    const int xcd  = bid & 7;
    const int slot = bid >> 3;                // 0..31
    const int b    = xcd >> 1;
    const int tp   = ((xcd & 1) << 5) | slot; // 0..63 tile-pair within batch

    const int tile    = w >> 2;          // 0,1
    const int quarter = w & 3;           // key quarter
    const int qbase   = tp * 64 + tile * 32;
    const int kbase   = quarter * 1024;

    const ushort* kgb = kg  + (size_t)b * N * 8;
    const ushort* qgb = qg  + (size_t)b * N * 8;
    const ushort* vgb = vtg + (size_t)b * C * N;

    // Q^T B-frag: B[c][q], lane: q = l&31, c = 8G+j (G=1 half zeroed; this
    // alone realizes the K=16 padding — K-side garbage multiplies zeros).
    s16x8 qf;
    {
        const s16x8 z8 = {};
        const s16x8 qv = *(const s16x8*)(qgb + (size_t)(qbase + q32) * 8);
        qf = g1 ? z8 : qv;
    }

    // K A-frag loader: A[key][c], lane: key = l&31
    auto kload = [&](int chunk) -> s16x8 {
        return *(const s16x8*)(kgb + (size_t)(kbase + chunk * CH + q32) * 8);
    };
    // V^T A-frag lanes: channel row (q32 / q32+32), element offset 16*ks+8G
    // (8G folded into the base pointer).
    const ushort* vrow0 = vgb + (size_t)q32 * N + 8 * G;
    const ushort* vrow1 = vgb + (size_t)(q32 + 32) * N + 8 * G;

    f32x16 acc0 = {}; f32x16 acc1 = {};
    float d0 = 0.f, d1 = 0.f, d2 = 0.f, d3 = 0.f;

    // chunk-ahead register prefetch
    s16x8 kcur = kload(0);
    s16x8 va0, va1, va2, va3;
    {
        va0 = *(const s16x8*)(vrow0 + kbase);
        va1 = *(const s16x8*)(vrow1 + kbase);
        va2 = *(const s16x8*)(vrow0 + kbase + 16);
        va3 = *(const s16x8*)(vrow1 + kbase + 16);
    }

#pragma unroll 2
    for (int c0 = 0; c0 < NC; ++c0) {
        // ---- prefetch chunk c0+1 (hidden under this chunk's compute) ------
        const int cn  = (c0 + 1 < NC) ? c0 + 1 : c0;
        const int kof = kbase + cn * CH;
        const s16x8 knx = kload(cn);
        const s16x8 vb0 = *(const s16x8*)(vrow0 + kof);
        const s16x8 vb1 = *(const s16x8*)(vrow1 + kof);
        const s16x8 vb2 = *(const s16x8*)(vrow0 + kof + 16);
        const s16x8 vb3 = *(const s16x8*)(vrow1 + kof + 16);

        // pacing barrier: keeps the 2 tile-waves of each quarter within ~1
        // chunk so their shared K/V stream stays L1-resident (raw s_barrier:
        // loads stay in flight across it).
        __builtin_amdgcn_s_barrier();

        // ---- QK^T: S^T(32k x 32q) = K(32x16) * Q^T(16x32) -----------------
        f32x16 sf = {};
        sf = __builtin_amdgcn_mfma_f32_32x32x16_bf16(kcur, qf, sf, 0, 0, 0);

        // ---- softmax numerators: scores pre-scaled, bare exp2 -------------
        // sf[r] = S^T[key=(r&3)+8*(r>>2)+4G][q32]; no max shift (|s| bounded).
        float p[16];
#pragma unroll
        for (int r = 0; r < 16; r++) p[r] = exp2_fast(sf[r]);
#pragma unroll
        for (int r = 0; r < 16; r += 4) {
            d0 += p[r]; d1 += p[r + 1]; d2 += p[r + 2]; d3 += p[r + 3];
        }

        // ---- PV: O^T += V^T * P^T over two 16-key steps -------------------
#pragma unroll
        for (int ks = 0; ks < 2; ++ks) {
            // B-frag: B[k][q], lane supplies keys 8G..8G+7 of this step.
            // Own quad packed locally; other half's quad via shfl_xor(32).
            uint wd[4];
#pragma unroll
            for (int i = 0; i < 2; i++) {
                const int base = 2 * i + 8 * ks;
                const uint XO = pk2(p[base + 0], p[base + 1]); // keys 4G-quad lo
                const uint XH = pk2(p[base + 4], p[base + 5]); // keys 4G-quad hi
                const uint Y  = g1 ? XO : XH;                  // exported quad
                const uint Z  = (uint)__shfl_xor((int)Y, 32);  // received quad
                wd[0 + i] = g1 ? Z : XO;
                wd[2 + i] = g1 ? XH : Z;
            }
            union { uint u[4]; s16x8 v; } bu;
            bu.u[0] = wd[0]; bu.u[1] = wd[1]; bu.u[2] = wd[2]; bu.u[3] = wd[3];

            const s16x8 a0 = ks ? va2 : va0;
            const s16x8 a1 = ks ? va3 : va1;
            acc0 = __builtin_amdgcn_mfma_f32_32x32x16_bf16(a0, bu.v, acc0, 0, 0, 0);
            acc1 = __builtin_amdgcn_mfma_f32_32x32x16_bf16(a1, bu.v, acc1, 0, 0, 0);
        }

        kcur = knx;
        va0 = vb0; va1 = vb1; va2 = vb2; va3 = vb3;
    }

    // ---- epilogue: fold halves, 4-way combine across key quarters ----------
    float dsum = (d0 + d1) + (d2 + d3);
    dsum += __shfl_xor(dsum, 32);      // both G halves hold wave denom(q32)

    if (quarter != 0) {
        float* row = &comb[tile][quarter - 1][l][0];
#pragma unroll
        for (int e = 0; e < 16; e++) row[e]      = acc0[e];
#pragma unroll
        for (int e = 0; e < 16; e++) row[16 + e] = acc1[e];
        if (l < 32) combd[tile][quarter - 1][l] = dsum;
    }
    __syncthreads();
    if (quarter == 0) {
        const float g    = gamma[0];
        const float dtot = dsum + combd[tile][0][q32]
                                + combd[tile][1][q32]
                                + combd[tile][2][q32];
        const float inv  = 1.0f / dtot;
        const float* r0  = &comb[tile][0][l][0];
        const float* r1  = &comb[tile][1][l][0];
        const float* r2  = &comb[tile][2][l][0];
#pragma unroll
        for (int r = 0; r < 16; r++) {
            const int crow = (r & 3) + 8 * (r >> 2) + 4 * G;   // D-layout row
            const size_t a0 = ((size_t)b * C + crow) * N + qbase + q32;
            const size_t a1 = ((size_t)b * C + crow + 32) * N + qbase + q32;
            const float o0 = (acc0[r] + r0[r]      + r1[r]      + r2[r])      * inv;
            const float o1 = (acc1[r] + r0[16 + r] + r1[16 + r] + r2[16 + r]) * inv;
            out[a0] = g * o0 + xt[a0];
            out[a1] = g * o1 + xt[a1];
        }
    }
}

extern "C" void kernel_launch(void* const* d_in, const int* in_sizes, int n_in,
                              void* d_out, int out_size, void* d_ws, size_t ws_size,
                              hipStream_t stream) {
    const float* xs    = (const float*)d_in[0];   // x_source (B,C,D,H,W)
    const float* xt    = (const float*)d_in[1];   // x_target
    const float* Wq    = (const float*)d_in[2];
    const float* bq    = (const float*)d_in[3];
    const float* Wk    = (const float*)d_in[4];
    const float* bk    = (const float*)d_in[5];
    const float* Wv    = (const float*)d_in[6];
    const float* bv    = (const float*)d_in[7];
    const float* gamma = (const float*)d_in[8];
    float* out = (float*)d_out;

    ushort* qg  = (ushort*)d_ws;                   // B*N*8
    ushort* kg  = qg + (size_t)B * N * 8;          // B*N*8
    ushort* vtg = kg + (size_t)B * N * 8;          // B*C*N

    proj_kernel<<<(B * N) / 32, 320, 0, stream>>>(xs, xt, Wq, bq, Wk, bk, Wv, bv,
                                                  qg, kg, vtg);
    attn_kernel<<<B * 64, 512, 0, stream>>>(qg, kg, vtg, xt, gamma, out);
}

// Round 7
// 113.961 us; speedup vs baseline: 1.1283x; 1.1283x over previous
//
#include <hip/hip_runtime.h>
#include <hip/hip_bf16.h>

// SpatialCrossBranchAttention — bf16 MFMA v7
// B=4, C=64, C8=8, N=4096.
// ws (ushort bf16): qg[B*N*8] | kg[B*N*8] | vf[B*128*2048]  = 2.5 MB
//
// v7 change vs v6 (which passed, attn=42.8us, latency-bound: MfmaUtil 8.9%,
// VALUBusy 22%): V is now stored in MFMA-A-FRAGMENT ORDER by proj —
// vf[b][chunk][ks][f][lane][j] — so attn's V loads are lane*16B coalesced
// (v6 scattered 64 lanes across 32 cache lines per load = TA serialization).
// Proj additionally stages W/biases in LDS (kills 128 global VMEM/thread).

typedef __attribute__((ext_vector_type(8)))  short s16x8;
typedef __attribute__((ext_vector_type(16))) float f32x16;

constexpr int B  = 4;
constexpr int C  = 64;
constexpr int N  = 4096;
constexpr int CH = 32;   // keys per chunk
constexpr int NC = 32;   // chunks per key-quarter (1024/32)

__device__ __forceinline__ ushort f2bf(float x) {
    union { __hip_bfloat16 h; ushort u; } cv;
    cv.h = __float2bfloat16(x);
    return cv.u;
}
__device__ __forceinline__ uint pk2(float a, float b) {   // -> v_cvt_pk_bf16_f32
    union { __hip_bfloat162 h2; uint u; } cv;
    cv.h2.x = __float2bfloat16(a);
    cv.h2.y = __float2bfloat16(b);
    return cv.u;
}
__device__ __forceinline__ float exp2_fast(float x) {
#if __has_builtin(__builtin_amdgcn_exp2f)
    return __builtin_amdgcn_exp2f(x);
#else
    float e;
    asm("v_exp_f32 %0, %1" : "=v"(e) : "v"(x));
    return e;
#endif
}

// ---------------------------------------------------------------------------
// Projections. Block = 320 threads = 10 groups x 32 tokens (= 1 key chunk).
// grp 0..7: v channels grp*8..+7 (from xs) -> vf fragment-order bf16
// grp 8   : k (from xs)                    -> kg (B,N,8) bf16
// grp 9   : q (from xt), PRE-SCALED log2e  -> qg (B,N,8) bf16
// W and biases staged in LDS (20.3 KB).
// ---------------------------------------------------------------------------
__global__ __launch_bounds__(320) void proj_kernel(
    const float* __restrict__ xs, const float* __restrict__ xt,
    const float* __restrict__ Wq, const float* __restrict__ bq,
    const float* __restrict__ Wk, const float* __restrict__ bk,
    const float* __restrict__ Wv, const float* __restrict__ bv,
    ushort* __restrict__ qg, ushort* __restrict__ kg, ushort* __restrict__ vf)
{
    __shared__ float sWv[64 * 64];
    __shared__ float sWk[8 * 64];
    __shared__ float sWq[8 * 64];
    __shared__ float sB[80];           // bv[64] | bk[8] | bq[8]

    const int tid = threadIdx.x;
    for (int i = tid; i < 4096; i += 320) sWv[i] = Wv[i];
    for (int i = tid; i < 512;  i += 320) { sWk[i] = Wk[i]; sWq[i] = Wq[i]; }
    if (tid < 64)                sB[tid] = bv[tid];
    else if (tid < 72)           sB[tid] = bk[tid - 64];
    else if (tid < 80)           sB[tid] = bq[tid - 72];
    __syncthreads();

    const int grp = tid >> 5;                 // 0..9
    const int tok = tid & 31;
    const int b   = blockIdx.x >> 7;          // 128 blocks per batch
    const int n   = ((blockIdx.x & 127) << 5) + tok;

    const float* Wsel; const float* bsel; const float* xsel;
    if (grp < 8)       { Wsel = sWv + grp * 8 * C; bsel = sB + grp * 8; xsel = xs; }
    else if (grp == 8) { Wsel = sWk;               bsel = sB + 64;      xsel = xs; }
    else               { Wsel = sWq;               bsel = sB + 72;      xsel = xt; }

    float acc[8];
#pragma unroll
    for (int j = 0; j < 8; j++) acc[j] = bsel[j];

    const float* xcol = xsel + (size_t)b * C * N + n;
#pragma unroll 2
    for (int ci = 0; ci < C; ci += 4) {
        float x0 = xcol[(size_t)(ci + 0) * N];
        float x1 = xcol[(size_t)(ci + 1) * N];
        float x2 = xcol[(size_t)(ci + 2) * N];
        float x3 = xcol[(size_t)(ci + 3) * N];
#pragma unroll
        for (int j = 0; j < 8; j++) {
            const float4 w4 = *(const float4*)&Wsel[j * C + ci];
            acc[j] += w4.x * x0 + w4.y * x1 + w4.z * x2 + w4.w * x3;
        }
    }

    if (grp < 8) {
        // fragment-order store: vf[b][c][ks][f][lane=Gd*32+ch32][j]
        const int c   = n >> 5;
        const int kk  = n & 31;
        const int ks  = kk >> 4;
        const int Gd  = (kk >> 3) & 1;
        const int j   = kk & 7;
        const int f   = grp >> 2;          // ch>>5
        const int cb  = (grp & 3) * 8;     // ch32 base
        ushort* base = vf + ((size_t)(b * 128 + c) * 2048) + ks * 1024 + f * 512 + j;
#pragma unroll
        for (int jc = 0; jc < 8; jc++)
            base[(size_t)(Gd * 32 + cb + jc) * 8] = f2bf(acc[jc]);
    } else {
        if (grp == 9) {   // fold log2(e) into Q so softmax uses raw exp2
#pragma unroll
            for (int j = 0; j < 8; j++) acc[j] *= 1.4426950408889634f;
        }
        uint4 wv;
        wv.x = pk2(acc[0], acc[1]); wv.y = pk2(acc[2], acc[3]);
        wv.z = pk2(acc[4], acc[5]); wv.w = pk2(acc[6], acc[7]);
        ushort* dst = (grp == 8 ? kg : qg) + ((size_t)b * N + n) * 8;
        *(uint4*)dst = wv;
    }
}

// ---------------------------------------------------------------------------
// Attention. Block = 512 threads = 8 waves: tile = w>>2 (2 query tiles of 32),
// quarter = w&3 (4 key quarters of 1024). Grid = B*64 = 256 blocks (1/CU),
// 2 waves/SIMD. The 2 tile-waves of a quarter share the K/V stream via L1.
// ---------------------------------------------------------------------------
__global__ __launch_bounds__(512, 2) void attn_kernel(
    const ushort* __restrict__ qg, const ushort* __restrict__ kg,
    const ushort* __restrict__ vf, const float* __restrict__ xt,
    const float* __restrict__ gamma, float* __restrict__ out)
{
    __shared__ float comb[2][3][64][33];   // 4-way combine, 49.5 KB, 33-stride
    __shared__ float combd[2][3][32];      // partial denominators

    const int tid  = threadIdx.x;
    const int w    = tid >> 6;        // 0..7
    const int l    = tid & 63;
    const int q32  = l & 31;
    const int G    = l >> 5;          // lane half-group
    const bool g1  = (G != 0);

    // XCD-aware decode: xcd = bid & 7; 2 XCDs per batch; bijective (256=32x8).
    const int bid  = blockIdx.x;
    const int xcd  = bid & 7;
    const int slot = bid >> 3;                // 0..31
    const int b    = xcd >> 1;
    const int tp   = ((xcd & 1) << 5) | slot; // 0..63 tile-pair within batch

    const int tile    = w >> 2;          // 0,1
    const int quarter = w & 3;           // key quarter
    const int qbase   = tp * 64 + tile * 32;
    const int kbase   = quarter * 1024;
    const int cbase   = quarter * 32;    // first chunk of this quarter

    const ushort* kgb = kg + (size_t)b * N * 8;
    const ushort* qgb = qg + (size_t)b * N * 8;
    const ushort* vfb = vf + (size_t)b * 128 * 2048;

    // Q^T B-frag: B[c][q], lane: q = l&31, c = 8G+j (G=1 half zeroed; this
    // alone realizes the K=16 padding — K-side garbage multiplies zeros).
    s16x8 qf;
    {
        const s16x8 z8 = {};
        const s16x8 qv = *(const s16x8*)(qgb + (size_t)(qbase + q32) * 8);
        qf = g1 ? z8 : qv;
    }

    // K A-frag loader: A[key][c], lane: key = l&31 (coalesced 16B/lane)
    auto kload = [&](int chunk) -> s16x8 {
        return *(const s16x8*)(kgb + (size_t)(kbase + chunk * CH + q32) * 8);
    };
    // V fragment loader: vf[chunk][ks][f][lane][8] -> lane*16B coalesced
    const ushort* vl = vfb + (size_t)l * 8;

    f32x16 acc0 = {}; f32x16 acc1 = {};
    float d0 = 0.f, d1 = 0.f, d2 = 0.f, d3 = 0.f;

    // chunk-ahead register prefetch
    s16x8 kcur = kload(0);
    s16x8 va0, va1, va2, va3;
    {
        const ushort* vc = vl + (size_t)cbase * 2048;
        va0 = *(const s16x8*)(vc + 0);      // ks0, ch 0..31
        va1 = *(const s16x8*)(vc + 512);    // ks0, ch 32..63
        va2 = *(const s16x8*)(vc + 1024);   // ks1, ch 0..31
        va3 = *(const s16x8*)(vc + 1536);   // ks1, ch 32..63
    }

#pragma unroll 2
    for (int c0 = 0; c0 < NC; ++c0) {
        // ---- prefetch chunk c0+1 (hidden under this chunk's compute) ------
        const int cn  = (c0 + 1 < NC) ? c0 + 1 : c0;
        const s16x8 knx = kload(cn);
        const ushort* vc = vl + (size_t)(cbase + cn) * 2048;
        const s16x8 vb0 = *(const s16x8*)(vc + 0);
        const s16x8 vb1 = *(const s16x8*)(vc + 512);
        const s16x8 vb2 = *(const s16x8*)(vc + 1024);
        const s16x8 vb3 = *(const s16x8*)(vc + 1536);

        // pacing barrier: keeps the 2 tile-waves of each quarter within ~1
        // chunk so their shared K/V stream stays L1-resident (raw s_barrier:
        // loads stay in flight across it).
        __builtin_amdgcn_s_barrier();

        // ---- QK^T: S^T(32k x 32q) = K(32x16) * Q^T(16x32) -----------------
        f32x16 sf = {};
        sf = __builtin_amdgcn_mfma_f32_32x32x16_bf16(kcur, qf, sf, 0, 0, 0);

        // ---- softmax numerators: scores pre-scaled, bare exp2 -------------
        // sf[r] = S^T[key=(r&3)+8*(r>>2)+4G][q32]; no max shift (|s| bounded).
        float p[16];
#pragma unroll
        for (int r = 0; r < 16; r++) p[r] = exp2_fast(sf[r]);
#pragma unroll
        for (int r = 0; r < 16; r += 4) {
            d0 += p[r]; d1 += p[r + 1]; d2 += p[r + 2]; d3 += p[r + 3];
        }

        // ---- PV: O^T += V^T * P^T over two 16-key steps -------------------
#pragma unroll
        for (int ks = 0; ks < 2; ++ks) {
            // B-frag: B[k][q], lane supplies keys 8G..8G+7 of this step.
            // Own quad packed locally; other half's quad via shfl_xor(32).
            uint wd[4];
#pragma unroll
            for (int i = 0; i < 2; i++) {
                const int base = 2 * i + 8 * ks;
                const uint XO = pk2(p[base + 0], p[base + 1]); // keys 4G-quad lo
                const uint XH = pk2(p[base + 4], p[base + 5]); // keys 4G-quad hi
                const uint Y  = g1 ? XO : XH;                  // exported quad
                const uint Z  = (uint)__shfl_xor((int)Y, 32);  // received quad
                wd[0 + i] = g1 ? Z : XO;
                wd[2 + i] = g1 ? XH : Z;
            }
            union { uint u[4]; s16x8 v; } bu;
            bu.u[0] = wd[0]; bu.u[1] = wd[1]; bu.u[2] = wd[2]; bu.u[3] = wd[3];

            const s16x8 a0 = ks ? va2 : va0;
            const s16x8 a1 = ks ? va3 : va1;
            acc0 = __builtin_amdgcn_mfma_f32_32x32x16_bf16(a0, bu.v, acc0, 0, 0, 0);
            acc1 = __builtin_amdgcn_mfma_f32_32x32x16_bf16(a1, bu.v, acc1, 0, 0, 0);
        }

        kcur = knx;
        va0 = vb0; va1 = vb1; va2 = vb2; va3 = vb3;
    }

    // ---- epilogue: fold halves, 4-way combine across key quarters ----------
    float dsum = (d0 + d1) + (d2 + d3);
    dsum += __shfl_xor(dsum, 32);      // both G halves hold wave denom(q32)

    if (quarter != 0) {
        float* row = &comb[tile][quarter - 1][l][0];
#pragma unroll
        for (int e = 0; e < 16; e++) row[e]      = acc0[e];
#pragma unroll
        for (int e = 0; e < 16; e++) row[16 + e] = acc1[e];
        if (l < 32) combd[tile][quarter - 1][l] = dsum;
    }
    __syncthreads();
    if (quarter == 0) {
        const float g    = gamma[0];
        const float dtot = dsum + combd[tile][0][q32]
                                + combd[tile][1][q32]
                                + combd[tile][2][q32];
        const float inv  = 1.0f / dtot;
        const float* r0  = &comb[tile][0][l][0];
        const float* r1  = &comb[tile][1][l][0];
        const float* r2  = &comb[tile][2][l][0];
#pragma unroll
        for (int r = 0; r < 16; r++) {
            const int crow = (r & 3) + 8 * (r >> 2) + 4 * G;   // D-layout row
            const size_t a0 = ((size_t)b * C + crow) * N + qbase + q32;
            const size_t a1 = ((size_t)b * C + crow + 32) * N + qbase + q32;
            const float o0 = (acc0[r] + r0[r]      + r1[r]      + r2[r])      * inv;
            const float o1 = (acc1[r] + r0[16 + r] + r1[16 + r] + r2[16 + r]) * inv;
            out[a0] = g * o0 + xt[a0];
            out[a1] = g * o1 + xt[a1];
        }
    }
}

extern "C" void kernel_launch(void* const* d_in, const int* in_sizes, int n_in,
                              void* d_out, int out_size, void* d_ws, size_t ws_size,
                              hipStream_t stream) {
    const float* xs    = (const float*)d_in[0];   // x_source (B,C,D,H,W)
    const float* xt    = (const float*)d_in[1];   // x_target
    const float* Wq    = (const float*)d_in[2];
    const float* bq    = (const float*)d_in[3];
    const float* Wk    = (const float*)d_in[4];
    const float* bk    = (const float*)d_in[5];
    const float* Wv    = (const float*)d_in[6];
    const float* bv    = (const float*)d_in[7];
    const float* gamma = (const float*)d_in[8];
    float* out = (float*)d_out;

    ushort* qg = (ushort*)d_ws;                    // B*N*8
    ushort* kg = qg + (size_t)B * N * 8;           // B*N*8
    ushort* vfp = kg + (size_t)B * N * 8;          // B*128*2048 (fragment order)

    proj_kernel<<<(B * N) / 32, 320, 0, stream>>>(xs, xt, Wq, bq, Wk, bk, Wv, bv,
                                                  qg, kg, vfp);
    attn_kernel<<<B * 64, 512, 0, stream>>>(qg, kg, vfp, xt, gamma, out);
}

// Round 8
// 110.729 us; speedup vs baseline: 1.1613x; 1.0292x over previous
//
#include <hip/hip_runtime.h>
#include <hip/hip_bf16.h>

// SpatialCrossBranchAttention — bf16 MFMA v8
// B=4, C=64, C8=8, N=4096.
// ws (ushort bf16): qg[B*N*8] | kg[B*N*8] | vf[B*128*2048]  = 2.5 MB
//
// v8 vs v7: attn waves fattened to 64 queries (2 subtiles) x 512 keys
// (8-way key split, no in-loop barrier) -> 10 MFMAs per 5 loads per chunk;
// P^T -> B-frag via v_permlane32_swap_b32 (VALU) instead of ds_bpermute +
// cndmasks; 8-way tree-combine epilogue. Proj V-store now LDS-staged and
// coalesced (uint4 per lane).

typedef __attribute__((ext_vector_type(8)))  short s16x8;
typedef __attribute__((ext_vector_type(16))) float f32x16;

constexpr int B  = 4;
constexpr int C  = 64;
constexpr int N  = 4096;
constexpr int CH = 32;   // keys per chunk
constexpr int NCW = 16;  // chunks per wave (512 keys)

__device__ __forceinline__ ushort f2bf(float x) {
    union { __hip_bfloat16 h; ushort u; } cv;
    cv.h = __float2bfloat16(x);
    return cv.u;
}
__device__ __forceinline__ uint pk2(float a, float b) {   // -> v_cvt_pk_bf16_f32
    union { __hip_bfloat162 h2; uint u; } cv;
    cv.h2.x = __float2bfloat16(a);
    cv.h2.y = __float2bfloat16(b);
    return cv.u;
}
__device__ __forceinline__ float exp2_fast(float x) {
#if __has_builtin(__builtin_amdgcn_exp2f)
    return __builtin_amdgcn_exp2f(x);
#else
    float e;
    asm("v_exp_f32 %0, %1" : "=v"(e) : "v"(x));
    return e;
#endif
}

// ---------------------------------------------------------------------------
// Projections. Block = 320 threads = 10 groups x 32 tokens (= 1 key chunk).
// grp 0..7: v channels grp*8..+7 (from xs) -> LDS tile -> coalesced vf store
// grp 8   : k (from xs)                    -> kg (B,N,8) bf16
// grp 9   : q (from xt), PRE-SCALED log2e  -> qg (B,N,8) bf16
// ---------------------------------------------------------------------------
__global__ __launch_bounds__(320) void proj_kernel(
    const float* __restrict__ xs, const float* __restrict__ xt,
    const float* __restrict__ Wq, const float* __restrict__ bq,
    const float* __restrict__ Wk, const float* __restrict__ bk,
    const float* __restrict__ Wv, const float* __restrict__ bv,
    ushort* __restrict__ qg, ushort* __restrict__ kg, ushort* __restrict__ vf)
{
    __shared__ float sWv[64 * 64];
    __shared__ float sWk[8 * 64];
    __shared__ float sWq[8 * 64];
    __shared__ float sB[80];            // bv[64] | bk[8] | bq[8]
    __shared__ ushort vt[32][68];       // V tile (tokens x channels), padded

    const int tid = threadIdx.x;
    for (int i = tid; i < 4096; i += 320) sWv[i] = Wv[i];
    for (int i = tid; i < 512;  i += 320) { sWk[i] = Wk[i]; sWq[i] = Wq[i]; }
    if (tid < 64)       sB[tid] = bv[tid];
    else if (tid < 72)  sB[tid] = bk[tid - 64];
    else if (tid < 80)  sB[tid] = bq[tid - 72];
    __syncthreads();

    const int grp = tid >> 5;                 // 0..9
    const int tok = tid & 31;
    const int b   = blockIdx.x >> 7;          // 128 chunks per batch
    const int c   = blockIdx.x & 127;         // key chunk index
    const int n   = (c << 5) + tok;

    const float* Wsel; const float* bsel; const float* xsel;
    if (grp < 8)       { Wsel = sWv + grp * 8 * C; bsel = sB + grp * 8; xsel = xs; }
    else if (grp == 8) { Wsel = sWk;               bsel = sB + 64;      xsel = xs; }
    else               { Wsel = sWq;               bsel = sB + 72;      xsel = xt; }

    float acc[8];
#pragma unroll
    for (int j = 0; j < 8; j++) acc[j] = bsel[j];

    const float* xcol = xsel + (size_t)b * C * N + n;
#pragma unroll 2
    for (int ci = 0; ci < C; ci += 4) {
        float x0 = xcol[(size_t)(ci + 0) * N];
        float x1 = xcol[(size_t)(ci + 1) * N];
        float x2 = xcol[(size_t)(ci + 2) * N];
        float x3 = xcol[(size_t)(ci + 3) * N];
#pragma unroll
        for (int j = 0; j < 8; j++) {
            const float4 w4 = *(const float4*)&Wsel[j * C + ci];
            acc[j] += w4.x * x0 + w4.y * x1 + w4.z * x2 + w4.w * x3;
        }
    }

    if (grp < 8) {
#pragma unroll
        for (int jc = 0; jc < 8; jc++) vt[tok][grp * 8 + jc] = f2bf(acc[jc]);
    } else {
        if (grp == 9) {   // fold log2(e) into Q so softmax uses raw exp2
#pragma unroll
            for (int j = 0; j < 8; j++) acc[j] *= 1.4426950408889634f;
        }
        uint4 wv;
        wv.x = pk2(acc[0], acc[1]); wv.y = pk2(acc[2], acc[3]);
        wv.z = pk2(acc[4], acc[5]); wv.w = pk2(acc[6], acc[7]);
        ushort* dst = (grp == 8 ? kg : qg) + ((size_t)b * N + n) * 8;
        *(uint4*)dst = wv;
    }
    __syncthreads();

    // cooperative fragment-order store: thread t -> vf[b][c][t*8 .. t*8+7]
    if (tid < 256) {
        const int ks = tid >> 7;
        const int f  = (tid >> 6) & 1;
        const int ln = tid & 63;
        const int ch = f * 32 + (ln & 31);
        const int kkb = ks * 16 + (ln >> 5) * 8;
        ushort u[8];
#pragma unroll
        for (int j = 0; j < 8; j++) u[j] = vt[kkb + j][ch];
        uint4 wv;
        wv.x = (uint)u[0] | ((uint)u[1] << 16);
        wv.y = (uint)u[2] | ((uint)u[3] << 16);
        wv.z = (uint)u[4] | ((uint)u[5] << 16);
        wv.w = (uint)u[6] | ((uint)u[7] << 16);
        *(uint4*)(vf + ((size_t)(b * 128 + c) * 2048) + tid * 8) = wv;
    }
}

// ---------------------------------------------------------------------------
// Attention. Block = 512 threads = 8 waves. Each wave: 64 queries (2 subtiles
// of 32) x 512 keys (its 1/8 key split), 16 chunks of 32 keys, no in-loop
// barrier. Grid = 256 blocks = 1/CU, 2 waves/SIMD. Tree-combine epilogue.
// ---------------------------------------------------------------------------
__global__ __launch_bounds__(512, 2) void attn_kernel(
    const ushort* __restrict__ qg, const ushort* __restrict__ kg,
    const ushort* __restrict__ vf, const float* __restrict__ xt,
    const float* __restrict__ gamma, float* __restrict__ out)
{
    __shared__ float cb[4][64][66];   // combine slots (ch x q), 67.6 KB
    __shared__ float cd[4][64];       // partial denominators

    const int tid  = threadIdx.x;
    const int w    = tid >> 6;        // 0..7 = key split
    const int l    = tid & 63;
    const int q32  = l & 31;
    const int G    = l >> 5;
    const bool g1  = (G != 0);

    // XCD-aware decode: 2 XCDs per batch; bijective (256 = 32 x 8).
    const int bid  = blockIdx.x;
    const int xcd  = bid & 7;
    const int b    = xcd >> 1;
    const int qt   = ((xcd & 1) << 5) | (bid >> 3);   // 0..63
    const int qbase = qt * 64;
    const int kbase = w * 512;

    const ushort* kgb = kg + (size_t)b * N * 8;
    const ushort* qgb = qg + (size_t)b * N * 8;
    const ushort* vfb = vf + (size_t)b * 128 * 2048;

    // Q^T B-frags (2 subtiles): B[c][q], lane q = l&31, c = 8G+j (G1 zeroed;
    // this realizes the K=16 padding — K-side garbage multiplies zeros).
    s16x8 qf0, qf1;
    {
        const s16x8 z8 = {};
        const s16x8 qa = *(const s16x8*)(qgb + (size_t)(qbase + q32) * 8);
        const s16x8 qb = *(const s16x8*)(qgb + (size_t)(qbase + 32 + q32) * 8);
        qf0 = g1 ? z8 : qa;
        qf1 = g1 ? z8 : qb;
    }

    auto kload = [&](int c) -> s16x8 {   // K A-frag: 512B, both halves same
        return *(const s16x8*)(kgb + (size_t)(kbase + c * CH + q32) * 8);
    };
    const ushort* vl = vfb + (size_t)l * 8;   // V frags: lane*16B coalesced

    f32x16 acc00 = {}, acc01 = {}, acc10 = {}, acc11 = {};
    float dn0 = 0.f, dn1 = 0.f;

    // one-chunk register prefetch
    s16x8 kcur = kload(0);
    s16x8 va00, va01, va10, va11;
    {
        const ushort* vc = vl + (size_t)(w * NCW) * 2048;
        va00 = *(const s16x8*)(vc + 0);      // ks0, ch 0..31
        va01 = *(const s16x8*)(vc + 512);    // ks0, ch 32..63
        va10 = *(const s16x8*)(vc + 1024);   // ks1, ch 0..31
        va11 = *(const s16x8*)(vc + 1536);   // ks1, ch 32..63
    }

#pragma unroll 2
    for (int c0 = 0; c0 < NCW; ++c0) {
        // ---- prefetch chunk c0+1 ------------------------------------------
        const int cn = (c0 + 1 < NCW) ? c0 + 1 : c0;
        const s16x8 knx = kload(cn);
        const ushort* vc = vl + (size_t)(w * NCW + cn) * 2048;
        const s16x8 vb00 = *(const s16x8*)(vc + 0);
        const s16x8 vb01 = *(const s16x8*)(vc + 512);
        const s16x8 vb10 = *(const s16x8*)(vc + 1024);
        const s16x8 vb11 = *(const s16x8*)(vc + 1536);

        // ---- QK^T for both q-subtiles -------------------------------------
        f32x16 sf0 = {}, sf1 = {};
        sf0 = __builtin_amdgcn_mfma_f32_32x32x16_bf16(kcur, qf0, sf0, 0, 0, 0);
        sf1 = __builtin_amdgcn_mfma_f32_32x32x16_bf16(kcur, qf1, sf1, 0, 0, 0);

        // ---- softmax numerators (pre-scaled -> bare exp2; no max shift) ---
        float p0[16], p1[16];
#pragma unroll
        for (int r = 0; r < 16; r++) p0[r] = exp2_fast(sf0[r]);
#pragma unroll
        for (int r = 0; r < 16; r++) p1[r] = exp2_fast(sf1[r]);
        dn0 += (((p0[0]+p0[1])+(p0[2]+p0[3])) + ((p0[4]+p0[5])+(p0[6]+p0[7])))
             + (((p0[8]+p0[9])+(p0[10]+p0[11])) + ((p0[12]+p0[13])+(p0[14]+p0[15])));
        dn1 += (((p1[0]+p1[1])+(p1[2]+p1[3])) + ((p1[4]+p1[5])+(p1[6]+p1[7])))
             + (((p1[8]+p1[9])+(p1[10]+p1[11])) + ((p1[12]+p1[13])+(p1[14]+p1[15])));

        // ---- PV: O^T += V * P^T, two 16-key steps, both subtiles ----------
        // B-frag build: LO_i = pk2(p[8ks+2i], p[8ks+2i+1]),
        //               HI_i = pk2(p[8ks+4+2i], p[8ks+4+2i+1]);
        // permlane32_swap(LO_i, HI_i) -> wd[i] = LO_i', wd[2+i] = HI_i'.
#pragma unroll
        for (int ks = 0; ks < 2; ++ks) {
            union { uint u[4]; s16x8 v; } b0, b1;
#pragma unroll
            for (int i = 0; i < 2; i++) {
                uint lo0 = pk2(p0[8 * ks + 2 * i],     p0[8 * ks + 2 * i + 1]);
                uint hi0 = pk2(p0[8 * ks + 4 + 2 * i], p0[8 * ks + 5 + 2 * i]);
                asm("v_permlane32_swap_b32 %0, %1" : "+v"(lo0), "+v"(hi0));
                b0.u[i] = lo0; b0.u[2 + i] = hi0;
                uint lo1 = pk2(p1[8 * ks + 2 * i],     p1[8 * ks + 2 * i + 1]);
                uint hi1 = pk2(p1[8 * ks + 4 + 2 * i], p1[8 * ks + 5 + 2 * i]);
                asm("v_permlane32_swap_b32 %0, %1" : "+v"(lo1), "+v"(hi1));
                b1.u[i] = lo1; b1.u[2 + i] = hi1;
            }
            const s16x8 a0 = ks ? va10 : va00;
            const s16x8 a1 = ks ? va11 : va01;
            acc00 = __builtin_amdgcn_mfma_f32_32x32x16_bf16(a0, b0.v, acc00, 0, 0, 0);
            acc01 = __builtin_amdgcn_mfma_f32_32x32x16_bf16(a1, b0.v, acc01, 0, 0, 0);
            acc10 = __builtin_amdgcn_mfma_f32_32x32x16_bf16(a0, b1.v, acc10, 0, 0, 0);
            acc11 = __builtin_amdgcn_mfma_f32_32x32x16_bf16(a1, b1.v, acc11, 0, 0, 0);
        }

        kcur = knx;
        va00 = vb00; va01 = vb01; va10 = vb10; va11 = vb11;
    }

    // ---- epilogue: fold G halves, tree-combine 8 key splits ----------------
    dn0 += __shfl_xor(dn0, 32);
    dn1 += __shfl_xor(dn1, 32);

    // helpers expanded inline (no divergent barriers: all guards, bars outside)
#define STORE_SLOT(S)                                                          \
    {                                                                          \
        float* s0 = &cb[S][0][0];                                              \
        _Pragma("unroll")                                                      \
        for (int r = 0; r < 16; r++) {                                         \
            const int ch = (r & 3) + 8 * (r >> 2) + 4 * G;                     \
            s0[(ch)      * 66 + q32]      = acc00[r];                          \
            s0[(ch + 32) * 66 + q32]      = acc01[r];                          \
            s0[(ch)      * 66 + 32 + q32] = acc10[r];                          \
            s0[(ch + 32) * 66 + 32 + q32] = acc11[r];                          \
        }                                                                      \
        if (!g1) { cd[S][q32] = dn0; cd[S][32 + q32] = dn1; }                  \
    }
#define ADD_SLOT(S)                                                            \
    {                                                                          \
        const float* s0 = &cb[S][0][0];                                        \
        _Pragma("unroll")                                                      \
        for (int r = 0; r < 16; r++) {                                         \
            const int ch = (r & 3) + 8 * (r >> 2) + 4 * G;                     \
            acc00[r] += s0[(ch)      * 66 + q32];                              \
            acc01[r] += s0[(ch + 32) * 66 + q32];                              \
            acc10[r] += s0[(ch)      * 66 + 32 + q32];                         \
            acc11[r] += s0[(ch + 32) * 66 + 32 + q32];                         \
        }                                                                      \
        dn0 += cd[S][q32];                                                     \
        dn1 += cd[S][32 + q32];                                                \
    }

    if (w >= 4) STORE_SLOT(w - 4);
    __syncthreads();
    if (w < 4) ADD_SLOT(w);
    __syncthreads();
    if (w == 2 || w == 3) STORE_SLOT(w - 2);
    __syncthreads();
    if (w < 2) ADD_SLOT(w);
    __syncthreads();
    if (w == 1) STORE_SLOT(0);
    __syncthreads();
    if (w == 0) {
        ADD_SLOT(0);
        const float g    = gamma[0];
        const float inv0 = 1.0f / dn0;
        const float inv1 = 1.0f / dn1;
#pragma unroll
        for (int r = 0; r < 16; r++) {
            const int ch = (r & 3) + 8 * (r >> 2) + 4 * G;
            const size_t a00 = ((size_t)b * C + ch)      * N + qbase + q32;
            const size_t a01 = ((size_t)b * C + ch + 32) * N + qbase + q32;
            const size_t a10 = a00 + 32;
            const size_t a11 = a01 + 32;
            out[a00] = g * (acc00[r] * inv0) + xt[a00];
            out[a01] = g * (acc01[r] * inv0) + xt[a01];
            out[a10] = g * (acc10[r] * inv1) + xt[a10];
            out[a11] = g * (acc11[r] * inv1) + xt[a11];
        }
    }
#undef STORE_SLOT
#undef ADD_SLOT
}

extern "C" void kernel_launch(void* const* d_in, const int* in_sizes, int n_in,
                              void* d_out, int out_size, void* d_ws, size_t ws_size,
                              hipStream_t stream) {
    const float* xs    = (const float*)d_in[0];   // x_source (B,C,D,H,W)
    const float* xt    = (const float*)d_in[1];   // x_target
    const float* Wq    = (const float*)d_in[2];
    const float* bq    = (const float*)d_in[3];
    const float* Wk    = (const float*)d_in[4];
    const float* bk    = (const float*)d_in[5];
    const float* Wv    = (const float*)d_in[6];
    const float* bv    = (const float*)d_in[7];
    const float* gamma = (const float*)d_in[8];
    float* out = (float*)d_out;

    ushort* qg  = (ushort*)d_ws;                   // B*N*8
    ushort* kg  = qg + (size_t)B * N * 8;          // B*N*8
    ushort* vfp = kg + (size_t)B * N * 8;          // B*128*2048 (fragment order)

    proj_kernel<<<(B * N) / 32, 320, 0, stream>>>(xs, xt, Wq, bq, Wk, bk, Wv, bv,
                                                  qg, kg, vfp);
    attn_kernel<<<B * 64, 512, 0, stream>>>(qg, kg, vfp, xt, gamma, out);
}

// Round 10
// 107.604 us; speedup vs baseline: 1.1950x; 1.0290x over previous
//
#include <hip/hip_runtime.h>
#include <hip/hip_bf16.h>

// SpatialCrossBranchAttention — bf16 MFMA v9 (resubmit; r9 was an infra
// failure: "container failed twice", kernel never ran)
// B=4, C=64, C8=8, N=4096.
// ws (ushort bf16): qg[B*N*8] | kg[B*N*8] | vf[B*128*2048]  = 2.5 MB
//
// v9 vs v8: attn chunk body processes the two q-subtiles SERIALLY to halve
// the live p/sf register set (v8 peaked ~230-250 VGPR at the 256 cap for
// 2 waves/SIMD -> suspected partial spill; both-pipes-idle counters fit).
// Plus s_setprio around MFMA clusters. Proj unchanged (isolates attn delta).

typedef __attribute__((ext_vector_type(8)))  short s16x8;
typedef __attribute__((ext_vector_type(16))) float f32x16;

constexpr int B  = 4;
constexpr int C  = 64;
constexpr int N  = 4096;
constexpr int CH = 32;   // keys per chunk
constexpr int NCW = 16;  // chunks per wave (512 keys)

__device__ __forceinline__ ushort f2bf(float x) {
    union { __hip_bfloat16 h; ushort u; } cv;
    cv.h = __float2bfloat16(x);
    return cv.u;
}
__device__ __forceinline__ uint pk2(float a, float b) {   // -> v_cvt_pk_bf16_f32
    union { __hip_bfloat162 h2; uint u; } cv;
    cv.h2.x = __float2bfloat16(a);
    cv.h2.y = __float2bfloat16(b);
    return cv.u;
}
__device__ __forceinline__ float exp2_fast(float x) {
#if __has_builtin(__builtin_amdgcn_exp2f)
    return __builtin_amdgcn_exp2f(x);
#else
    float e;
    asm("v_exp_f32 %0, %1" : "=v"(e) : "v"(x));
    return e;
#endif
}

// ---------------------------------------------------------------------------
// Projections. Block = 320 threads = 10 groups x 32 tokens (= 1 key chunk).
// grp 0..7: v channels grp*8..+7 (from xs) -> LDS tile -> coalesced vf store
// grp 8   : k (from xs)                    -> kg (B,N,8) bf16
// grp 9   : q (from xt), PRE-SCALED log2e  -> qg (B,N,8) bf16
// ---------------------------------------------------------------------------
__global__ __launch_bounds__(320) void proj_kernel(
    const float* __restrict__ xs, const float* __restrict__ xt,
    const float* __restrict__ Wq, const float* __restrict__ bq,
    const float* __restrict__ Wk, const float* __restrict__ bk,
    const float* __restrict__ Wv, const float* __restrict__ bv,
    ushort* __restrict__ qg, ushort* __restrict__ kg, ushort* __restrict__ vf)
{
    __shared__ float sWv[64 * 64];
    __shared__ float sWk[8 * 64];
    __shared__ float sWq[8 * 64];
    __shared__ float sB[80];            // bv[64] | bk[8] | bq[8]
    __shared__ ushort vt[32][68];       // V tile (tokens x channels), padded

    const int tid = threadIdx.x;
    for (int i = tid; i < 4096; i += 320) sWv[i] = Wv[i];
    for (int i = tid; i < 512;  i += 320) { sWk[i] = Wk[i]; sWq[i] = Wq[i]; }
    if (tid < 64)       sB[tid] = bv[tid];
    else if (tid < 72)  sB[tid] = bk[tid - 64];
    else if (tid < 80)  sB[tid] = bq[tid - 72];
    __syncthreads();

    const int grp = tid >> 5;                 // 0..9
    const int tok = tid & 31;
    const int b   = blockIdx.x >> 7;          // 128 chunks per batch
    const int c   = blockIdx.x & 127;         // key chunk index
    const int n   = (c << 5) + tok;

    const float* Wsel; const float* bsel; const float* xsel;
    if (grp < 8)       { Wsel = sWv + grp * 8 * C; bsel = sB + grp * 8; xsel = xs; }
    else if (grp == 8) { Wsel = sWk;               bsel = sB + 64;      xsel = xs; }
    else               { Wsel = sWq;               bsel = sB + 72;      xsel = xt; }

    float acc[8];
#pragma unroll
    for (int j = 0; j < 8; j++) acc[j] = bsel[j];

    const float* xcol = xsel + (size_t)b * C * N + n;
#pragma unroll 2
    for (int ci = 0; ci < C; ci += 4) {
        float x0 = xcol[(size_t)(ci + 0) * N];
        float x1 = xcol[(size_t)(ci + 1) * N];
        float x2 = xcol[(size_t)(ci + 2) * N];
        float x3 = xcol[(size_t)(ci + 3) * N];
#pragma unroll
        for (int j = 0; j < 8; j++) {
            const float4 w4 = *(const float4*)&Wsel[j * C + ci];
            acc[j] += w4.x * x0 + w4.y * x1 + w4.z * x2 + w4.w * x3;
        }
    }

    if (grp < 8) {
#pragma unroll
        for (int jc = 0; jc < 8; jc++) vt[tok][grp * 8 + jc] = f2bf(acc[jc]);
    } else {
        if (grp == 9) {   // fold log2(e) into Q so softmax uses raw exp2
#pragma unroll
            for (int j = 0; j < 8; j++) acc[j] *= 1.4426950408889634f;
        }
        uint4 wv;
        wv.x = pk2(acc[0], acc[1]); wv.y = pk2(acc[2], acc[3]);
        wv.z = pk2(acc[4], acc[5]); wv.w = pk2(acc[6], acc[7]);
        ushort* dst = (grp == 8 ? kg : qg) + ((size_t)b * N + n) * 8;
        *(uint4*)dst = wv;
    }
    __syncthreads();

    // cooperative fragment-order store: thread t -> vf[b][c][t*8 .. t*8+7]
    if (tid < 256) {
        const int ks = tid >> 7;
        const int f  = (tid >> 6) & 1;
        const int ln = tid & 63;
        const int ch = f * 32 + (ln & 31);
        const int kkb = ks * 16 + (ln >> 5) * 8;
        ushort u[8];
#pragma unroll
        for (int j = 0; j < 8; j++) u[j] = vt[kkb + j][ch];
        uint4 wv;
        wv.x = (uint)u[0] | ((uint)u[1] << 16);
        wv.y = (uint)u[2] | ((uint)u[3] << 16);
        wv.z = (uint)u[4] | ((uint)u[5] << 16);
        wv.w = (uint)u[6] | ((uint)u[7] << 16);
        *(uint4*)(vf + ((size_t)(b * 128 + c) * 2048) + tid * 8) = wv;
    }
}

// ---------------------------------------------------------------------------
// Attention. Block = 512 threads = 8 waves = 8-way key split; each wave:
// 64 queries (2 subtiles of 32, processed SERIALLY per chunk) x 512 keys.
// Grid = 256 blocks = 1/CU, 2 waves/SIMD. Tree-combine epilogue.
// ---------------------------------------------------------------------------
__global__ __launch_bounds__(512, 2) void attn_kernel(
    const ushort* __restrict__ qg, const ushort* __restrict__ kg,
    const ushort* __restrict__ vf, const float* __restrict__ xt,
    const float* __restrict__ gamma, float* __restrict__ out)
{
    __shared__ float cb[4][64][66];   // combine slots (ch x q), 67.6 KB
    __shared__ float cd[4][64];       // partial denominators

    const int tid  = threadIdx.x;
    const int w    = tid >> 6;        // 0..7 = key split
    const int l    = tid & 63;
    const int q32  = l & 31;
    const int G    = l >> 5;
    const bool g1  = (G != 0);

    // XCD-aware decode: 2 XCDs per batch; bijective (256 = 32 x 8).
    const int bid  = blockIdx.x;
    const int xcd  = bid & 7;
    const int b    = xcd >> 1;
    const int qt   = ((xcd & 1) << 5) | (bid >> 3);   // 0..63
    const int qbase = qt * 64;
    const int kbase = w * 512;

    const ushort* kgb = kg + (size_t)b * N * 8;
    const ushort* qgb = qg + (size_t)b * N * 8;
    const ushort* vfb = vf + (size_t)b * 128 * 2048;

    // Q^T B-frags (2 subtiles): B[c][q], lane q = l&31, c = 8G+j (G1 zeroed;
    // this realizes the K=16 padding — K-side garbage multiplies zeros).
    s16x8 qf0, qf1;
    {
        const s16x8 z8 = {};
        const s16x8 qa = *(const s16x8*)(qgb + (size_t)(qbase + q32) * 8);
        const s16x8 qb = *(const s16x8*)(qgb + (size_t)(qbase + 32 + q32) * 8);
        qf0 = g1 ? z8 : qa;
        qf1 = g1 ? z8 : qb;
    }

    auto kload = [&](int c) -> s16x8 {   // K A-frag: 512B, both halves same
        return *(const s16x8*)(kgb + (size_t)(kbase + c * CH + q32) * 8);
    };
    const ushort* vl = vfb + (size_t)l * 8;   // V frags: lane*16B coalesced

    f32x16 acc00 = {}, acc01 = {}, acc10 = {}, acc11 = {};
    float dn0 = 0.f, dn1 = 0.f;

    // one-chunk register prefetch
    s16x8 kcur = kload(0);
    s16x8 va00, va01, va10, va11;
    {
        const ushort* vc = vl + (size_t)(w * NCW) * 2048;
        va00 = *(const s16x8*)(vc + 0);      // ks0, ch 0..31
        va01 = *(const s16x8*)(vc + 512);    // ks0, ch 32..63
        va10 = *(const s16x8*)(vc + 1024);   // ks1, ch 0..31
        va11 = *(const s16x8*)(vc + 1536);   // ks1, ch 32..63
    }

#pragma unroll 4
    for (int c0 = 0; c0 < NCW; ++c0) {
        // ---- prefetch chunk c0+1 (in flight across this chunk's compute) --
        const int cn = (c0 + 1 < NCW) ? c0 + 1 : c0;
        const s16x8 knx = kload(cn);
        const ushort* vc = vl + (size_t)(w * NCW + cn) * 2048;
        const s16x8 vb00 = *(const s16x8*)(vc + 0);
        const s16x8 vb01 = *(const s16x8*)(vc + 512);
        const s16x8 vb10 = *(const s16x8*)(vc + 1024);
        const s16x8 vb11 = *(const s16x8*)(vc + 1536);

        // ================= q-subtile 0 (serial: halves live p/sf set) ======
        {
            f32x16 sf = {};
            __builtin_amdgcn_s_setprio(1);
            sf = __builtin_amdgcn_mfma_f32_32x32x16_bf16(kcur, qf0, sf, 0, 0, 0);
            __builtin_amdgcn_s_setprio(0);
            float p[16];
#pragma unroll
            for (int r = 0; r < 16; r++) p[r] = exp2_fast(sf[r]);
            dn0 += (((p[0]+p[1])+(p[2]+p[3])) + ((p[4]+p[5])+(p[6]+p[7])))
                 + (((p[8]+p[9])+(p[10]+p[11])) + ((p[12]+p[13])+(p[14]+p[15])));
#pragma unroll
            for (int ks = 0; ks < 2; ++ks) {
                union { uint u[4]; s16x8 v; } bf;
#pragma unroll
                for (int i = 0; i < 2; i++) {
                    uint lo = pk2(p[8 * ks + 2 * i],     p[8 * ks + 2 * i + 1]);
                    uint hi = pk2(p[8 * ks + 4 + 2 * i], p[8 * ks + 5 + 2 * i]);
                    asm("v_permlane32_swap_b32 %0, %1" : "+v"(lo), "+v"(hi));
                    bf.u[i] = lo; bf.u[2 + i] = hi;
                }
                const s16x8 a0 = ks ? va10 : va00;
                const s16x8 a1 = ks ? va11 : va01;
                __builtin_amdgcn_s_setprio(1);
                acc00 = __builtin_amdgcn_mfma_f32_32x32x16_bf16(a0, bf.v, acc00, 0, 0, 0);
                acc01 = __builtin_amdgcn_mfma_f32_32x32x16_bf16(a1, bf.v, acc01, 0, 0, 0);
                __builtin_amdgcn_s_setprio(0);
            }
        }
        // ================= q-subtile 1 ======================================
        {
            f32x16 sf = {};
            __builtin_amdgcn_s_setprio(1);
            sf = __builtin_amdgcn_mfma_f32_32x32x16_bf16(kcur, qf1, sf, 0, 0, 0);
            __builtin_amdgcn_s_setprio(0);
            float p[16];
#pragma unroll
            for (int r = 0; r < 16; r++) p[r] = exp2_fast(sf[r]);
            dn1 += (((p[0]+p[1])+(p[2]+p[3])) + ((p[4]+p[5])+(p[6]+p[7])))
                 + (((p[8]+p[9])+(p[10]+p[11])) + ((p[12]+p[13])+(p[14]+p[15])));
#pragma unroll
            for (int ks = 0; ks < 2; ++ks) {
                union { uint u[4]; s16x8 v; } bf;
#pragma unroll
                for (int i = 0; i < 2; i++) {
                    uint lo = pk2(p[8 * ks + 2 * i],     p[8 * ks + 2 * i + 1]);
                    uint hi = pk2(p[8 * ks + 4 + 2 * i], p[8 * ks + 5 + 2 * i]);
                    asm("v_permlane32_swap_b32 %0, %1" : "+v"(lo), "+v"(hi));
                    bf.u[i] = lo; bf.u[2 + i] = hi;
                }
                const s16x8 a0 = ks ? va10 : va00;
                const s16x8 a1 = ks ? va11 : va01;
                __builtin_amdgcn_s_setprio(1);
                acc10 = __builtin_amdgcn_mfma_f32_32x32x16_bf16(a0, bf.v, acc10, 0, 0, 0);
                acc11 = __builtin_amdgcn_mfma_f32_32x32x16_bf16(a1, bf.v, acc11, 0, 0, 0);
                __builtin_amdgcn_s_setprio(0);
            }
        }

        kcur = knx;
        va00 = vb00; va01 = vb01; va10 = vb10; va11 = vb11;
    }

    // ---- epilogue: fold G halves, tree-combine 8 key splits ----------------
    dn0 += __shfl_xor(dn0, 32);
    dn1 += __shfl_xor(dn1, 32);

#define STORE_SLOT(S)                                                          \
    {                                                                          \
        float* s0 = &cb[S][0][0];                                              \
        _Pragma("unroll")                                                      \
        for (int r = 0; r < 16; r++) {                                         \
            const int ch = (r & 3) + 8 * (r >> 2) + 4 * G;                     \
            s0[(ch)      * 66 + q32]      = acc00[r];                          \
            s0[(ch + 32) * 66 + q32]      = acc01[r];                          \
            s0[(ch)      * 66 + 32 + q32] = acc10[r];                          \
            s0[(ch + 32) * 66 + 32 + q32] = acc11[r];                          \
        }                                                                      \
        if (!g1) { cd[S][q32] = dn0; cd[S][32 + q32] = dn1; }                  \
    }
#define ADD_SLOT(S)                                                            \
    {                                                                          \
        const float* s0 = &cb[S][0][0];                                        \
        _Pragma("unroll")                                                      \
        for (int r = 0; r < 16; r++) {                                         \
            const int ch = (r & 3) + 8 * (r >> 2) + 4 * G;                     \
            acc00[r] += s0[(ch)      * 66 + q32];                              \
            acc01[r] += s0[(ch + 32) * 66 + q32];                              \
            acc10[r] += s0[(ch)      * 66 + 32 + q32];                         \
            acc11[r] += s0[(ch + 32) * 66 + 32 + q32];                         \
        }                                                                      \
        dn0 += cd[S][q32];                                                     \
        dn1 += cd[S][32 + q32];                                                \
    }

    if (w >= 4) STORE_SLOT(w - 4);
    __syncthreads();
    if (w < 4) ADD_SLOT(w);
    __syncthreads();
    if (w == 2 || w == 3) STORE_SLOT(w - 2);
    __syncthreads();
    if (w < 2) ADD_SLOT(w);
    __syncthreads();
    if (w == 1) STORE_SLOT(0);
    __syncthreads();
    if (w == 0) {
        ADD_SLOT(0);
        const float g    = gamma[0];
        const float inv0 = 1.0f / dn0;
        const float inv1 = 1.0f / dn1;
#pragma unroll
        for (int r = 0; r < 16; r++) {
            const int ch = (r & 3) + 8 * (r >> 2) + 4 * G;
            const size_t a00 = ((size_t)b * C + ch)      * N + qbase + q32;
            const size_t a01 = ((size_t)b * C + ch + 32) * N + qbase + q32;
            const size_t a10 = a00 + 32;
            const size_t a11 = a01 + 32;
            out[a00] = g * (acc00[r] * inv0) + xt[a00];
            out[a01] = g * (acc01[r] * inv0) + xt[a01];
            out[a10] = g * (acc10[r] * inv1) + xt[a10];
            out[a11] = g * (acc11[r] * inv1) + xt[a11];
        }
    }
#undef STORE_SLOT
#undef ADD_SLOT
}

extern "C" void kernel_launch(void* const* d_in, const int* in_sizes, int n_in,
                              void* d_out, int out_size, void* d_ws, size_t ws_size,
                              hipStream_t stream) {
    const float* xs    = (const float*)d_in[0];   // x_source (B,C,D,H,W)
    const float* xt    = (const float*)d_in[1];   // x_target
    const float* Wq    = (const float*)d_in[2];
    const float* bq    = (const float*)d_in[3];
    const float* Wk    = (const float*)d_in[4];
    const float* bk    = (const float*)d_in[5];
    const float* Wv    = (const float*)d_in[6];
    const float* bv    = (const float*)d_in[7];
    const float* gamma = (const float*)d_in[8];
    float* out = (float*)d_out;

    ushort* qg  = (ushort*)d_ws;                   // B*N*8
    ushort* kg  = qg + (size_t)B * N * 8;          // B*N*8
    ushort* vfp = kg + (size_t)B * N * 8;          // B*128*2048 (fragment order)

    proj_kernel<<<(B * N) / 32, 320, 0, stream>>>(xs, xt, Wq, bq, Wk, bk, Wv, bv,
                                                  qg, kg, vfp);
    attn_kernel<<<B * 64, 512, 0, stream>>>(qg, kg, vfp, xt, gamma, out);
}